// Round 1
// baseline (118.132 us; speedup 1.0000x reference)
//
#include <hip/hip_runtime.h>
#include <stdint.h>

// BinaryTreeLogicNet: out = sigmoid(tree_gcd(sigmoid(x @ W^T - 2)) * w_out + b_out)
// M=65536 rows, L=256 leaves.
// R8: register-diet rev of R7 (spill theory).
//   R7 held raw fp32 A-prefetch (16 VGPR) live across the MFMA loop next to
//   acc (64) + packed frags + transients under a 128-VGPR cap -> likely
//   scratch spill in the hot loop (only hypothesis consistent with 113.7 µs
//   vs ~15-20 µs composed roofline).
//   - ALL A-frags pre-packed to bf16 before the K loop: af[4][2] short8
//     (32 VGPR), loaded 2-batches-deep with sched_barrier fences.
//   - kt loop fully unrolled (static af / LDS-buffer indices; rule #20).
//   - Redundant kt=3 A reload removed (-16 MB HBM); final barrier removed.
//   - W image / swizzle / tree epilogue identical to R7 (verified:
//     absmax 0.00390625).

#define EPS 1e-6f
#define LOG2E 1.44269504088896340736f
#define PARAM_OFF 131072            // byte offset of param table in img

typedef __attribute__((ext_vector_type(8))) short short8;
typedef __attribute__((ext_vector_type(4))) short short4_t;
typedef __attribute__((ext_vector_type(4))) float float4_t;

__device__ __forceinline__ float fast_sigmoid(float z) {
    float e = __builtin_amdgcn_exp2f(-z * LOG2E);
    return __builtin_amdgcn_rcpf(1.0f + e);
}

__device__ __forceinline__ short f2bf(float f) {   // fp32 -> bf16 RNE
    uint32_t u = __builtin_bit_cast(uint32_t, f);
    u += 0x7FFFu + ((u >> 16) & 1u);
    return (short)(u >> 16);
}

__device__ __forceinline__ short8 pack8(float4 a, float4 b) {
    short8 s;
    s[0] = f2bf(a.x); s[1] = f2bf(a.y); s[2] = f2bf(a.z); s[3] = f2bf(a.w);
    s[4] = f2bf(b.x); s[5] = f2bf(b.y); s[6] = f2bf(b.z); s[7] = f2bf(b.w);
    return s;
}

__device__ __forceinline__ float ggcd(float l, float r, float lam) {
    float a = fabsf(l) + EPS;
    float b = fabsf(r) + EPS;
    float mn = fminf(a, b);
    float mx = fmaxf(a, b);
    return fmaf(lam, mn - mx, mx);   // lam*mn + (1-lam)*mx
}

__device__ __forceinline__ void lds16(const void* g, void* l) {
    __builtin_amdgcn_global_load_lds(
        (const __attribute__((address_space(1))) unsigned int*)g,
        (__attribute__((address_space(3))) unsigned int*)l, 16, 0, 0);
}

// tree levels 1-4 on one 16-acc row-group; acc consumed in place
__device__ __forceinline__ void tree_reduce(float4_t acc[16], int c0,
                                            const float4* pv, float res[4]) {
    #pragma unroll
    for (int t = 0; t < 16; ++t) {
        #pragma unroll
        for (int r = 0; r < 4; ++r) acc[t][r] = fast_sigmoid(acc[t][r] - 2.0f);
    }
    #pragma unroll
    for (int tp = 0; tp < 8; ++tp) {          // level 1 (off 0)
        float4 p = pv[c0 * 8 + tp];
        #pragma unroll
        for (int r = 0; r < 4; ++r)
            acc[tp][r] = ggcd(acc[2*tp][r] * p.x, acc[2*tp+1][r] * p.y, p.z);
    }
    #pragma unroll
    for (int tp = 0; tp < 4; ++tp) {          // level 2 (off 128)
        float4 p = pv[128 + c0 * 4 + tp];
        #pragma unroll
        for (int r = 0; r < 4; ++r)
            acc[tp][r] = ggcd(acc[2*tp][r] * p.x, acc[2*tp+1][r] * p.y, p.z);
    }
    #pragma unroll
    for (int tp = 0; tp < 2; ++tp) {          // level 3 (off 192)
        float4 p = pv[192 + c0 * 2 + tp];
        #pragma unroll
        for (int r = 0; r < 4; ++r)
            acc[tp][r] = ggcd(acc[2*tp][r] * p.x, acc[2*tp+1][r] * p.y, p.z);
    }
    {                                          // level 4 (off 224)
        float4 p = pv[224 + c0];
        #pragma unroll
        for (int r = 0; r < 4; ++r)
            res[r] = ggcd(acc[0][r] * p.x, acc[1][r] * p.y, p.z);
    }
}

// ---- pre-kernel: build swizzled bf16 W image + packed params in d_ws ----
// img byte a (a = kt*32768 + j*128 + cpos*16 + h*8):
//   holds W[swap(j)][kt*64 + (cpos^(j&7))*8 + h*4 .. +4) as bf16x4
__global__ __launch_bounds__(256)
void convert_w(const float* __restrict__ Wl, const float* __restrict__ wts,
               const float* __restrict__ bia, char* __restrict__ img) {
    int i = blockIdx.x * 256 + threadIdx.x;   // 64 blocks -> 16384 threads x 8 B
    int a = i * 8;
    int kt   = a >> 15;
    int s    = a & 32767;
    int j    = s >> 7;
    int b    = s & 127;
    int cpos = b >> 4;
    int h    = (b >> 3) & 1;
    int c    = cpos ^ (j & 7);
    int k    = kt * 64 + c * 8 + h * 4;
    int src  = ((j & 15) << 4) | (j >> 4);    // nibble-swap (involution)
    float4 w4 = *(const float4*)&Wl[src * 256 + k];
    short4_t s4;
    s4.x = f2bf(w4.x); s4.y = f2bf(w4.y); s4.z = f2bf(w4.z); s4.w = f2bf(w4.w);
    *(short4_t*)&img[a] = s4;

    if (i < 255) {
        float4* pv = (float4*)(img + PARAM_OFF);
        pv[i] = make_float4(wts[2 * i], wts[2 * i + 1], fast_sigmoid(bia[i]), 0.f);
    } else if (i == 255) {
        ((float4*)(img + PARAM_OFF))[255] = make_float4(0.f, 0.f, 0.f, 0.f);
    }
}

// ---- main kernel ----
__global__ __launch_bounds__(512, 4)
void btln_main(const float* __restrict__ x, const char* __restrict__ img,
               const float* __restrict__ wout, const float* __restrict__ bout,
               float* __restrict__ out) {
    __shared__ short Wt[2][16384];           // 2 x 32 KB W K-tiles
    __shared__ float4 pv[256];               // 4 KB packed (w0,w1,lam)

    const int tid  = threadIdx.x;
    const int lane = tid & 63;
    const int wv   = tid >> 6;               // wave 0..7
    const int c0   = lane & 15;
    const int q    = lane >> 4;

    if (tid < 256) pv[tid] = ((const float4*)(img + PARAM_OFF))[tid];

    // issue tile 0 (wave wv owns 4 KB: 4 x (64 lanes x 16 B))
    const char* gW = img + wv * 4096 + lane * 16;
    {
        char* l = (char*)&Wt[0][wv * 2048];
        #pragma unroll
        for (int it = 0; it < 4; ++it)
            lds16(gW + it * 1024, l + it * 1024);
    }

    const int rowbase = blockIdx.x * 128 + wv * 16;
    const float* xr = x + (size_t)(rowbase + c0) * 256;

    // ---- preload + pack ALL A-frags (af[kt]: k-range kt*64..kt*64+63) ----
    // 2-batches-deep pipeline; sched_barrier keeps transient fp32 regs <= 32.
    short8 af[4][2];
    {
        float4 p0, p1, p2, p3, q0, q1, q2, q3;
        p0 = *(const float4*)(xr + q * 8);
        p1 = *(const float4*)(xr + q * 8 + 4);
        p2 = *(const float4*)(xr + 32 + q * 8);
        p3 = *(const float4*)(xr + 32 + q * 8 + 4);
        q0 = *(const float4*)(xr + 64 + q * 8);
        q1 = *(const float4*)(xr + 64 + q * 8 + 4);
        q2 = *(const float4*)(xr + 96 + q * 8);
        q3 = *(const float4*)(xr + 96 + q * 8 + 4);
        af[0][0] = pack8(p0, p1); af[0][1] = pack8(p2, p3);
        __builtin_amdgcn_sched_barrier(0);
        p0 = *(const float4*)(xr + 128 + q * 8);
        p1 = *(const float4*)(xr + 128 + q * 8 + 4);
        p2 = *(const float4*)(xr + 160 + q * 8);
        p3 = *(const float4*)(xr + 160 + q * 8 + 4);
        af[1][0] = pack8(q0, q1); af[1][1] = pack8(q2, q3);
        __builtin_amdgcn_sched_barrier(0);
        q0 = *(const float4*)(xr + 192 + q * 8);
        q1 = *(const float4*)(xr + 192 + q * 8 + 4);
        q2 = *(const float4*)(xr + 224 + q * 8);
        q3 = *(const float4*)(xr + 224 + q * 8 + 4);
        af[2][0] = pack8(p0, p1); af[2][1] = pack8(p2, p3);
        __builtin_amdgcn_sched_barrier(0);
        af[3][0] = pack8(q0, q1); af[3][1] = pack8(q2, q3);
    }

    float4_t acc[16];
    #pragma unroll
    for (int t = 0; t < 16; ++t) acc[t] = (float4_t){0.f, 0.f, 0.f, 0.f};

    __syncthreads();                          // tile 0 resident (vmcnt drained)

    const int vx = c0 & 7;

    // ---- K loop, fully unrolled (static af / buffer indices) ----
#define KSTEP(kt, LAST)                                                       \
    {                                                                         \
        const short* cur = Wt[(kt) & 1];                                      \
        if (!(LAST)) {                                                        \
            char* l = (char*)&Wt[((kt) + 1) & 1][wv * 2048];                  \
            const char* g = gW + ((kt) + 1) * 32768;                          \
            lds16(g, l);                                                      \
            lds16(g + 1024, l + 1024);                                        \
            lds16(g + 2048, l + 2048);                                        \
            lds16(g + 3072, l + 3072);                                        \
        }                                                                     \
        _Pragma("unroll")                                                     \
        for (int t = 0; t < 16; ++t) {                                        \
            const short* base = &cur[(t * 16 + c0) * 64];                     \
            short8 bf0 = *(const short8*)&base[(q ^ vx) * 8];                 \
            short8 bf1 = *(const short8*)&base[((q + 4) ^ vx) * 8];           \
            acc[t] = __builtin_amdgcn_mfma_f32_16x16x32_bf16(                 \
                af[kt][0], bf0, acc[t], 0, 0, 0);                             \
            acc[t] = __builtin_amdgcn_mfma_f32_16x16x32_bf16(                 \
                af[kt][1], bf1, acc[t], 0, 0, 0);                             \
        }                                                                     \
        if (!(LAST)) __syncthreads();                                         \
    }

    KSTEP(0, 0)
    KSTEP(1, 0)
    KSTEP(2, 0)
    KSTEP(3, 1)
#undef KSTEP

    // ---- epilogue: leaf sigmoid + tree (acc[t][r]: row q*4+r, leaf c0*16+t) ----
    float res[4];
    tree_reduce(acc, c0, pv, res);

    const int offs[4] = {240, 248, 252, 254};
    #pragma unroll
    for (int k = 0; k < 4; ++k) {             // levels 5-8: butterfly across c0
        float4 p = pv[offs[k] + (c0 >> (k + 1))];
        bool isLeft = ((c0 >> k) & 1) == 0;
        #pragma unroll
        for (int r = 0; r < 4; ++r) {
            float other = __shfl_xor(res[r], 1 << k, 64);
            float lf = isLeft ? res[r] : other;
            float rt = isLeft ? other  : res[r];
            res[r] = ggcd(lf * p.x, rt * p.y, p.z);
        }
    }

    if (c0 == 0) {
        const float wo = wout[0];
        const float bo = bout[0];
        #pragma unroll
        for (int r = 0; r < 4; ++r)
            out[rowbase + q * 4 + r] = fast_sigmoid(fmaf(res[r], wo, bo));
    }
}

extern "C" void kernel_launch(void* const* d_in, const int* in_sizes, int n_in,
                              void* d_out, int out_size, void* d_ws, size_t ws_size,
                              hipStream_t stream) {
    const float* x   = (const float*)d_in[0];
    const float* Wl  = (const float*)d_in[1];
    const float* wts = (const float*)d_in[2];
    const float* bia = (const float*)d_in[3];
    const float* wo  = (const float*)d_in[4];
    const float* bo  = (const float*)d_in[5];
    float* out = (float*)d_out;
    char* img = (char*)d_ws;                  // 128 KB W image + 4 KB params

    convert_w<<<dim3(64), dim3(256), 0, stream>>>(Wl, wts, bia, img);

    const int rows = out_size;                // 65536
    dim3 grid(rows / 128), block(512);        // 512 blocks x 8 waves, 2 blocks/CU
    btln_main<<<grid, block, 0, stream>>>(x, img, wo, bo, out);
}